// Round 1
// baseline (107176.697 us; speedup 1.0000x reference)
//
#include <hip/hip_runtime.h>

// ---------------- problem constants ----------------
#define TDEC   200
#define NB     16      // batch
#define TENC   512
#define DENC   512
#define PRE    256
#define RNN    1024
#define ATTD   128
#define NFILT  32

// ---------------- ws layout (float offsets) ----------------
#define PM_OFF   0u          // pm_t[16][128][512]
#define INP_OFF  1048576u    // inp[200][16][256]
#define HA_OFF   1867776u    // h_a[2][16][1024]
#define HD_OFF   1900544u    // h_d[2][16][1024]
#define CA_OFF   1933312u    // c_a[16][1024]
#define CD_OFF   1949696u    // c_d[16][1024]
#define CTX_OFF  1966080u    // ctx[16][512]
#define WB_OFF   1974272u    // w[16][512]
#define WC_OFF   1982464u    // wcum[16][512]
#define BAR_OFF  1990656u    // barrier state (576 u32, padded)
#define LOC_OFF  1991232u    // loc[16][32][512]
#define PE_OFF   2253376u    // pe[16][16][512]
#define ZLEN_F   123456u     // zero region: HA..BAR inclusive

#define BAR_ROOT 512
#define BAR_GEN  544

__device__ __forceinline__ float sigm(float x)   { return 1.0f / (1.0f + __expf(-x)); }
__device__ __forceinline__ float tanh_f(float x) { return 1.0f - 2.0f / (__expf(2.0f * x) + 1.0f); }

// ---- two-level grid barrier (deterministic data, agent-scope) ----
__device__ __forceinline__ void grid_barrier(unsigned* bar)
{
    __syncthreads();
    if (threadIdx.x == 0) {
        __threadfence();
        unsigned g = __hip_atomic_load(&bar[BAR_GEN], __ATOMIC_RELAXED, __HIP_MEMORY_SCOPE_AGENT);
        const int leaf = (blockIdx.x & 15) * 32;
        if (__hip_atomic_fetch_add(&bar[leaf], 1u, __ATOMIC_ACQ_REL, __HIP_MEMORY_SCOPE_AGENT) == 15u) {
            if (__hip_atomic_fetch_add(&bar[BAR_ROOT], 1u, __ATOMIC_ACQ_REL, __HIP_MEMORY_SCOPE_AGENT) == 15u) {
                // last block: reset counters, release new generation
                #pragma unroll
                for (int i = 0; i < 16; ++i)
                    __hip_atomic_store(&bar[i * 32], 0u, __ATOMIC_RELAXED, __HIP_MEMORY_SCOPE_AGENT);
                __hip_atomic_store(&bar[BAR_ROOT], 0u, __ATOMIC_RELAXED, __HIP_MEMORY_SCOPE_AGENT);
                __hip_atomic_store(&bar[BAR_GEN], g + 1u, __ATOMIC_RELEASE, __HIP_MEMORY_SCOPE_AGENT);
            } else {
                while (__hip_atomic_load(&bar[BAR_GEN], __ATOMIC_RELAXED, __HIP_MEMORY_SCOPE_AGENT) == g)
                    __builtin_amdgcn_s_sleep(2);
                __threadfence();
            }
        } else {
            while (__hip_atomic_load(&bar[BAR_GEN], __ATOMIC_RELAXED, __HIP_MEMORY_SCOPE_AGENT) == g)
                __builtin_amdgcn_s_sleep(2);
            __threadfence();
        }
    }
    __syncthreads();
}

// ---- 16 gate-rows x 16 batches FMA micro-tile over a 64-float K window ----
__device__ __forceinline__ void fma16x4(float acc[16][4],
    const float* __restrict__ wp, int wrs, int j0,
    const float* __restrict__ ip, int irs, int ko, int l16, int g16)
{
    const int kk = ko + l16 * 4;
    const float4 iv0 = *(const float4*)(ip + (g16 * 4 + 0) * irs + kk);
    const float4 iv1 = *(const float4*)(ip + (g16 * 4 + 1) * irs + kk);
    const float4 iv2 = *(const float4*)(ip + (g16 * 4 + 2) * irs + kk);
    const float4 iv3 = *(const float4*)(ip + (g16 * 4 + 3) * irs + kk);
    #pragma unroll
    for (int r = 0; r < 16; ++r) {
        const int row = (r & 3) * 1024 + j0 + (r >> 2);
        const float4 w4 = *(const float4*)(wp + row * wrs + kk);
        acc[r][0] += w4.x * iv0.x + w4.y * iv0.y + w4.z * iv0.z + w4.w * iv0.w;
        acc[r][1] += w4.x * iv1.x + w4.y * iv1.y + w4.z * iv1.z + w4.w * iv1.w;
        acc[r][2] += w4.x * iv2.x + w4.y * iv2.y + w4.z * iv2.z + w4.w * iv2.w;
        acc[r][3] += w4.x * iv3.x + w4.y * iv3.y + w4.z * iv3.z + w4.w * iv3.w;
    }
}

// ---------------- precompute: pm_t[b][f][tt] = sum_d mem[b][tt][d]*Wm[f][d] ----------------
__global__ __launch_bounds__(256) void k_pm(const float* __restrict__ mem,
                                            const float* __restrict__ Wm,
                                            float* __restrict__ pm)
{
    const int bid = blockIdx.x;            // 512 blocks
    const int b = bid >> 5, ch = bid & 31; // 16 tt per block
    const int tid = threadIdx.x;
    const int tt0 = ch * 16;
    __shared__ float ml[16][512];
    for (int i = tid; i < 16 * 128; i += 256) {
        const int r = i >> 7, c4 = (i & 127) * 4;
        *(float4*)&ml[r][c4] = *(const float4*)(mem + (size_t)(b * 512 + tt0 + r) * 512 + c4);
    }
    __syncthreads();
    const int f = tid & 127, th = tid >> 7;
    float acc[8] = {0, 0, 0, 0, 0, 0, 0, 0};
    const float* wr = Wm + f * 512;
    for (int d = 0; d < 512; d += 4) {
        const float4 w4 = *(const float4*)(wr + d);
        #pragma unroll
        for (int i = 0; i < 8; ++i) {
            const float4 m4 = *(const float4*)&ml[th * 8 + i][d];
            acc[i] += w4.x * m4.x + w4.y * m4.y + w4.z * m4.z + w4.w * m4.w;
        }
    }
    #pragma unroll
    for (int i = 0; i < 8; ++i)
        pm[(size_t)(b * 128 + f) * 512 + tt0 + th * 8 + i] = acc[i];
}

// ---------------- precompute: prenet ----------------
__global__ __launch_bounds__(256) void k_prenet(const float* __restrict__ di,
                                                const float* __restrict__ W1,
                                                const float* __restrict__ W2,
                                                float* __restrict__ inp)
{
    const int t = blockIdx.x;  // 0..199
    const int tid = threadIdx.x;
    float* inpT = inp + (size_t)t * (NB * PRE);
    if (t == 0) {
        for (int i = tid; i < NB * PRE; i += 256) inpT[i] = 0.0f;
        return;
    }
    const int s = t - 1;
    __shared__ float xs[16][240];
    __shared__ float h1[16][256];
    for (int i = tid; i < 16 * 240; i += 256) {
        const int b = i / 240, j2 = i % 240;
        xs[b][j2] = di[(size_t)b * 48000 + (j2 % 80) * 600 + s * 3 + j2 / 80];
    }
    __syncthreads();
    const int j = tid;
    {
        float acc[16];
        #pragma unroll
        for (int b = 0; b < 16; ++b) acc[b] = 0.0f;
        const float* wr = W1 + j * 240;
        for (int k = 0; k < 240; k += 4) {
            const float4 w4 = *(const float4*)(wr + k);
            #pragma unroll
            for (int b = 0; b < 16; ++b) {
                const float4 x4 = *(const float4*)&xs[b][k];
                acc[b] += w4.x * x4.x + w4.y * x4.y + w4.z * x4.z + w4.w * x4.w;
            }
        }
        #pragma unroll
        for (int b = 0; b < 16; ++b) h1[b][j] = fmaxf(acc[b], 0.0f);
    }
    __syncthreads();
    {
        float acc[16];
        #pragma unroll
        for (int b = 0; b < 16; ++b) acc[b] = 0.0f;
        const float* wr = W2 + j * 256;
        for (int k = 0; k < 256; k += 4) {
            const float4 w4 = *(const float4*)(wr + k);
            #pragma unroll
            for (int b = 0; b < 16; ++b) {
                const float4 x4 = *(const float4*)&h1[b][k];
                acc[b] += w4.x * x4.x + w4.y * x4.y + w4.z * x4.z + w4.w * x4.w;
            }
        }
        #pragma unroll
        for (int b = 0; b < 16; ++b) inpT[b * 256 + j] = fmaxf(acc[b], 0.0f);
    }
}

// ---------------- persistent decoder kernel ----------------
__global__ __launch_bounds__(512) void k_main(
    const float* __restrict__ mem,  const int* __restrict__ mlen,
    const float* __restrict__ awih, const float* __restrict__ awhh,
    const float* __restrict__ abih, const float* __restrict__ abhh,
    const float* __restrict__ dwih, const float* __restrict__ dwhh,
    const float* __restrict__ dbih, const float* __restrict__ dbhh,
    const float* __restrict__ wq,   const float* __restrict__ vat,
    const float* __restrict__ cw,   const float* __restrict__ ldw,
    const float* __restrict__ pjw,  const float* __restrict__ pjb,
    float* __restrict__ ws, float* __restrict__ out)
{
    const int tid  = threadIdx.x;
    const int bid  = blockIdx.x;
    const int wid  = tid >> 6;
    const int lane = tid & 63;
    const int l16  = lane & 15;
    const int g16  = lane >> 4;

    float* pmT  = ws + PM_OFF;
    float* inp  = ws + INP_OFF;
    float* haB  = ws + HA_OFF;
    float* hdB  = ws + HD_OFF;
    float* caB  = ws + CA_OFF;
    float* cdB  = ws + CD_OFF;
    float* ctxB = ws + CTX_OFF;
    float* wBf  = ws + WB_OFF;
    float* wcB  = ws + WC_OFF;
    float* locB = ws + LOC_OFF;
    float* peB  = ws + PE_OFF;
    unsigned* bar = (unsigned*)(ws + BAR_OFF);
    float* outMel = out;
    float* outAl  = out + 768000;

    __shared__ float smem[2080];

    for (int t = 0; t <= TDEC; ++t) {
        const int cur = t & 1, prv = cur ^ 1;
        const float* haP  = haB + prv * (NB * RNN);  // h_a(t-1)
        float*       haC  = haB + cur * (NB * RNN);  // h_a(t)
        const float* hdP2 = hdB + cur * (NB * RNN);  // h_d(t-2)
        float*       hdW  = hdB + prv * (NB * RNN);  // h_d(t-1)

        // ================= P1: attLSTM(t), decLSTM(t-1), conv(t) =================
        {
            const int j0 = bid * 4;
            const bool isDec = wid >= 4;
            const int q = wid & 3;
            const bool act = isDec ? (t >= 1) : (t < TDEC);
            if (act) {
                float acc[16][4];
                #pragma unroll
                for (int r = 0; r < 16; ++r) { acc[r][0] = 0; acc[r][1] = 0; acc[r][2] = 0; acc[r][3] = 0; }
                if (!isDec) {
                    const float* inpT = inp + (size_t)t * (NB * PRE);
                    #pragma unroll
                    for (int it = 0; it < 7; ++it) {
                        const int kb = q * 448 + it * 64;
                        if (kb < 256)      fma16x4(acc, awih,        768,  j0, inpT, 256,  kb,        l16, g16);
                        else if (kb < 768) fma16x4(acc, awih + 256,  768,  j0, ctxB, 512,  kb - 256,  l16, g16);
                        else               fma16x4(acc, awhh,        1024, j0, haP,  1024, kb - 768,  l16, g16);
                    }
                } else {
                    #pragma unroll
                    for (int it = 0; it < 10; ++it) {
                        const int kb = q * 640 + it * 64;
                        if (kb < 1024)      fma16x4(acc, dwih,         1536, j0, haP,  1024, kb,         l16, g16);
                        else if (kb < 1536) fma16x4(acc, dwih + 1024,  1536, j0, ctxB, 512,  kb - 1024,  l16, g16);
                        else                fma16x4(acc, dwhh,         1024, j0, hdP2, 1024, kb - 1536,  l16, g16);
                    }
                }
                #pragma unroll
                for (int m = 1; m <= 8; m <<= 1) {
                    #pragma unroll
                    for (int r = 0; r < 16; ++r) {
                        #pragma unroll
                        for (int b2 = 0; b2 < 4; ++b2)
                            acc[r][b2] += __shfl_xor(acc[r][b2], m, 16);
                    }
                }
                if (l16 == 0) {
                    #pragma unroll
                    for (int r = 0; r < 16; ++r) {
                        #pragma unroll
                        for (int b2 = 0; b2 < 4; ++b2)
                            smem[(wid * 16 + r) * 16 + g16 * 4 + b2] = acc[r][b2];
                    }
                }
            }
            __syncthreads();
            if (tid < 128) {
                const int isd = tid >> 6;
                const int cell = tid & 63;
                const int jl = cell >> 4, b = cell & 15;
                const bool act2 = isd ? (t >= 1) : (t < TDEC);
                if (act2) {
                    const int j = j0 + jl;
                    const float* bih = isd ? dbih : abih;
                    const float* bhh = isd ? dbhh : abhh;
                    float g4[4];
                    #pragma unroll
                    for (int g = 0; g < 4; ++g) {
                        const int r = jl * 4 + g;
                        float s = 0;
                        #pragma unroll
                        for (int w = 0; w < 4; ++w) s += smem[((isd * 4 + w) * 16 + r) * 16 + b];
                        g4[g] = s + bih[g * 1024 + j] + bhh[g * 1024 + j];
                    }
                    float* cb = isd ? cdB : caB;
                    float* hb = isd ? hdW : haC;
                    const float ii = sigm(g4[0]);
                    const float ff = sigm(g4[1]);
                    const float gg = tanh_f(g4[2]);
                    const float oo = sigm(g4[3]);
                    const float co = cb[b * RNN + j];
                    const float cn = ff * co + ii * gg;
                    cb[b * RNN + j] = cn;
                    hb[b * RNN + j] = oo * tanh_f(cn);
                }
            }
            if (t < TDEC) {
                // location conv: loc[b][c][tt]
                const int b = bid >> 4;
                const int c = (bid & 15) * 2 + (tid >> 8);
                const int ttb = tid & 255;
                const float* wr = wBf + b * 512;
                const float* wc2 = wcB + b * 512;
                const float* cwc = cw + c * 62;
                #pragma unroll
                for (int h = 0; h < 2; ++h) {
                    const int tt = ttb + h * 256;
                    float a = 0;
                    #pragma unroll
                    for (int kk = 0; kk < 31; ++kk) {
                        const int ix = tt + kk - 15;
                        if (ix >= 0 && ix < 512)
                            a += wr[ix] * cwc[kk] + wc2[ix] * cwc[31 + kk];
                    }
                    locB[(b * 32 + c) * 512 + tt] = a;
                }
            }
        }
        grid_barrier(bar);

        // ================= P2: q-slice + partial energies; proj(t-1) =================
        {
            if (t < TDEC) {
                const int b = bid >> 4, fc = bid & 15;
                {
                    const int f = fc * 8 + wid;
                    const float* wqr = wq + f * 1024;
                    const float* hac = haC + b * 1024;
                    float a = 0;
                    #pragma unroll
                    for (int it = 0; it < 4; ++it) {
                        const int k = it * 256 + lane * 4;
                        const float4 w4 = *(const float4*)(wqr + k);
                        const float4 h4 = *(const float4*)(hac + k);
                        a += w4.x * h4.x + w4.y * h4.y + w4.z * h4.z + w4.w * h4.w;
                    }
                    #pragma unroll
                    for (int m = 1; m <= 32; m <<= 1) a += __shfl_xor(a, m, 64);
                    if (lane == 0) smem[wid] = a;
                }
                __syncthreads();
                {
                    const int tt = tid;
                    float lc[32];
                    const float* lr = locB + b * (32 * 512);
                    #pragma unroll
                    for (int c2 = 0; c2 < 32; ++c2) lc[c2] = lr[c2 * 512 + tt];
                    const float* pmr = pmT + (size_t)(b * 128 + fc * 8) * 512;
                    float pes = 0;
                    #pragma unroll
                    for (int f_ = 0; f_ < 8; ++f_) {
                        const float* lw = ldw + (fc * 8 + f_) * 32;
                        float pl = 0;
                        #pragma unroll
                        for (int c2 = 0; c2 < 32; ++c2) pl += lc[c2] * lw[c2];
                        const float x = smem[f_] + pl + pmr[f_ * 512 + tt];
                        pes += vat[fc * 8 + f_] * tanh_f(x);
                    }
                    peB[(fc * 16 + b) * 512 + tt] = pes;
                }
            }
            if (t >= 1 && bid < 240) {
                const int jo = bid;
                const int b0 = wid * 2, b1 = b0 + 1;
                const float* pwr = pjw + jo * 1536;
                float a0 = 0, a1 = 0;
                #pragma unroll
                for (int it = 0; it < 6; ++it) {
                    const int k = it * 256 + lane * 4;
                    const float4 w4 = *(const float4*)(pwr + k);
                    const float* s0 = (it < 4) ? (hdW + b0 * 1024 + k) : (ctxB + b0 * 512 + (k - 1024));
                    const float* s1 = (it < 4) ? (hdW + b1 * 1024 + k) : (ctxB + b1 * 512 + (k - 1024));
                    const float4 x0 = *(const float4*)s0;
                    const float4 x1 = *(const float4*)s1;
                    a0 += w4.x * x0.x + w4.y * x0.y + w4.z * x0.z + w4.w * x0.w;
                    a1 += w4.x * x1.x + w4.y * x1.y + w4.z * x1.z + w4.w * x1.w;
                }
                #pragma unroll
                for (int m = 1; m <= 32; m <<= 1) { a0 += __shfl_xor(a0, m, 64); a1 += __shfl_xor(a1, m, 64); }
                if (lane == 0) {
                    const int m_ = jo % 80;
                    const int u = (t - 1) * 3 + jo / 80;
                    const float bv = pjb[jo];
                    outMel[(size_t)b0 * 48000 + m_ * 600 + u] = a0 + bv;
                    outMel[(size_t)b1 * 48000 + m_ * 600 + u] = a1 + bv;
                }
            }
        }
        if (t == TDEC) break;
        grid_barrier(bar);

        // ================= P3: softmax + context + w updates (one block per b) =================
        {
            if (bid < NB) {
                const int b = bid;
                float* pl_ = smem;        // [512]
                float* red = smem + 512;  // [9]
                const int tt = tid;
                float e = 0;
                #pragma unroll
                for (int fc = 0; fc < 16; ++fc) e += peB[(fc * 16 + b) * 512 + tt];
                const float p = (tt < mlen[b]) ? __expf(e) : 0.0f;
                pl_[tt] = p;
                float s = p;
                #pragma unroll
                for (int m = 1; m <= 32; m <<= 1) s += __shfl_xor(s, m, 64);
                if (lane == 0) red[wid] = s;
                __syncthreads();
                if (tid == 0) {
                    float d = 0;
                    #pragma unroll
                    for (int w = 0; w < 8; ++w) d += red[w];
                    red[8] = 1.0f / d;
                }
                __syncthreads();
                const float rd = red[8];
                {
                    const int d = tid;
                    const float* mr = mem + (size_t)b * (512 * 512);
                    float a = 0;
                    for (int t2 = 0; t2 < 512; t2 += 4) {
                        const float4 p4 = *(const float4*)&pl_[t2];
                        a += p4.x * mr[(size_t)(t2 + 0) * 512 + d];
                        a += p4.y * mr[(size_t)(t2 + 1) * 512 + d];
                        a += p4.z * mr[(size_t)(t2 + 2) * 512 + d];
                        a += p4.w * mr[(size_t)(t2 + 3) * 512 + d];
                    }
                    ctxB[b * 512 + d] = a * rd;
                }
                {
                    const float wn = pl_[tt] * rd;
                    wBf[b * 512 + tt] = wn;
                    wcB[b * 512 + tt] += wn;
                    outAl[(size_t)b * (200 * 512) + (size_t)t * 512 + tt] = wn;
                }
            }
            grid_barrier(bar);
        }
    }
}

extern "C" void kernel_launch(void* const* d_in, const int* in_sizes, int n_in,
                              void* d_out, int out_size, void* d_ws, size_t ws_size,
                              hipStream_t stream)
{
    (void)in_sizes; (void)n_in; (void)out_size; (void)ws_size;
    const float* mem  = (const float*)d_in[0];
    const float* di   = (const float*)d_in[1];
    const int*   mlen = (const int*)d_in[2];
    const float* pw1  = (const float*)d_in[3];
    const float* pw2  = (const float*)d_in[4];
    const float* awih = (const float*)d_in[5];
    const float* awhh = (const float*)d_in[6];
    const float* abih = (const float*)d_in[7];
    const float* abhh = (const float*)d_in[8];
    const float* dwih = (const float*)d_in[9];
    const float* dwhh = (const float*)d_in[10];
    const float* dbih = (const float*)d_in[11];
    const float* dbhh = (const float*)d_in[12];
    const float* wqp  = (const float*)d_in[13];
    const float* wmp  = (const float*)d_in[14];
    const float* vat  = (const float*)d_in[15];
    const float* cwp  = (const float*)d_in[16];
    const float* ldwp = (const float*)d_in[17];
    const float* pjw  = (const float*)d_in[18];
    const float* pjb  = (const float*)d_in[19];
    float* ws  = (float*)d_ws;
    float* out = (float*)d_out;

    // zero recurrent state + barrier region
    hipMemsetAsync(ws + HA_OFF, 0, ZLEN_F * sizeof(float), stream);
    hipLaunchKernelGGL(k_pm, dim3(512), dim3(256), 0, stream, mem, wmp, ws + PM_OFF);
    hipLaunchKernelGGL(k_prenet, dim3(200), dim3(256), 0, stream, di, pw1, pw2, ws + INP_OFF);

    void* args[] = { (void*)&mem, (void*)&mlen, (void*)&awih, (void*)&awhh,
                     (void*)&abih, (void*)&abhh, (void*)&dwih, (void*)&dwhh,
                     (void*)&dbih, (void*)&dbhh, (void*)&wqp, (void*)&vat,
                     (void*)&cwp, (void*)&ldwp, (void*)&pjw, (void*)&pjb,
                     (void*)&ws, (void*)&out };
    hipLaunchCooperativeKernel((const void*)k_main, dim3(256), dim3(512), args, 0, stream);
}

// Round 2
// 83968.958 us; speedup vs baseline: 1.2764x; 1.2764x over previous
//
#include <hip/hip_runtime.h>

// ---------------- problem constants ----------------
#define TDEC   200
#define NB     16      // batch
#define PRE    256
#define RNN    1024

// ---------------- ws layout (float offsets) ----------------
#define PM_OFF   0u          // pm_t[16][128][512]
#define INP_OFF  1048576u    // inp[200][16][256]
#define HA_OFF   1867776u    // h_a[2][16][1024]
#define HD_OFF   1900544u    // h_d[2][16][1024]
#define CA_OFF   1933312u    // c_a[16][1024]
#define CD_OFF   1949696u    // c_d[16][1024]
#define CTX_OFF  1966080u    // ctx[16][512]
#define WB_OFF   1974272u    // w[16][512]
#define WC_OFF   1982464u    // wcum[16][512]
#define BAR_OFF  1990656u    // barrier state (576 u32)
#define LOC_OFF  1991232u    // loc[b][tt][c] 16*512*32 (transposed)
#define PE_OFF   2253376u    // pe[b][tt][fc] 16*512*16 (transposed)
#define ZLEN_F   123456u     // zero region: HA..BAR inclusive

typedef unsigned long long u64;
union F2u { u64 u; float f[2]; };

// ---- coherent (cross-XCD) accessors: relaxed agent scope => sc-bit loads/stores,
// ---- NO buffer_wbl2/buffer_inv cache maintenance ----
__device__ __forceinline__ u64 ldc8(const float* p) {
    return __hip_atomic_load((u64*)p, __ATOMIC_RELAXED, __HIP_MEMORY_SCOPE_AGENT);
}
__device__ __forceinline__ float ldc4(const float* p) {
    return __hip_atomic_load((float*)p, __ATOMIC_RELAXED, __HIP_MEMORY_SCOPE_AGENT);
}
__device__ __forceinline__ void stc4(float* p, float v) {
    __hip_atomic_store(p, v, __ATOMIC_RELAXED, __HIP_MEMORY_SCOPE_AGENT);
}

__device__ __forceinline__ float sigm(float x)   { return 1.0f / (1.0f + __expf(-x)); }
__device__ __forceinline__ float tanh_f(float x) { return 1.0f - 2.0f / (__expf(2.0f * x) + 1.0f); }

// ---- fully-relaxed monotonic 2-level grid barrier ----
// Release: __syncthreads() drains each wave's vmcnt (coherent stores acked at LLC)
// before tid0's flag RMW issues. Acquire: data is re-read with sc-bit loads (LLC),
// so no invalidate needed. Counters monotonic => no reset race.
__device__ __forceinline__ void grid_barrier(unsigned* bar, unsigned g)
{
    __syncthreads();
    if (threadIdx.x == 0) {
        const int leaf = (blockIdx.x & 15) * 32;
        const unsigned tgt = g * 16u + 15u;
        if (__hip_atomic_fetch_add(&bar[leaf], 1u, __ATOMIC_RELAXED, __HIP_MEMORY_SCOPE_AGENT) == tgt) {
            if (__hip_atomic_fetch_add(&bar[512], 1u, __ATOMIC_RELAXED, __HIP_MEMORY_SCOPE_AGENT) == tgt) {
                __hip_atomic_store(&bar[544], g + 1u, __ATOMIC_RELAXED, __HIP_MEMORY_SCOPE_AGENT);
            } else {
                while (__hip_atomic_load(&bar[544], __ATOMIC_RELAXED, __HIP_MEMORY_SCOPE_AGENT) != g + 1u)
                    __builtin_amdgcn_s_sleep(1);
            }
        } else {
            while (__hip_atomic_load(&bar[544], __ATOMIC_RELAXED, __HIP_MEMORY_SCOPE_AGENT) != g + 1u)
                __builtin_amdgcn_s_sleep(1);
        }
    }
    __syncthreads();
}

// ---- 16 gate-rows x 16 batches over a 64-float K window ----
struct A16 { u64 d[8]; };
struct Src { const float* ap; const float* wp; int irs, wrs; };

__device__ __forceinline__ A16 load_slice(const float* p, int irs) {
    A16 a;
    #pragma unroll
    for (int b = 0; b < 4; ++b) {
        const float* q = p + b * irs;
        a.d[2 * b]     = ldc8(q);
        a.d[2 * b + 1] = ldc8(q + 2);
    }
    return a;
}

__device__ __forceinline__ void fma_slice(float acc[16][4],
    const float* __restrict__ wrow, int wrs, const A16& a)
{
    float av[16];
    #pragma unroll
    for (int b = 0; b < 4; ++b) {
        F2u lo, hi; lo.u = a.d[2 * b]; hi.u = a.d[2 * b + 1];
        av[b * 4 + 0] = lo.f[0]; av[b * 4 + 1] = lo.f[1];
        av[b * 4 + 2] = hi.f[0]; av[b * 4 + 3] = hi.f[1];
    }
    #pragma unroll
    for (int r = 0; r < 16; ++r) {
        const float4 w4 = *(const float4*)(wrow + (size_t)((r & 3) * 1024 + (r >> 2)) * wrs);
        #pragma unroll
        for (int b = 0; b < 4; ++b)
            acc[r][b] += w4.x * av[b * 4] + w4.y * av[b * 4 + 1] + w4.z * av[b * 4 + 2] + w4.w * av[b * 4 + 3];
    }
}

__device__ __forceinline__ Src att_src(int kb, const float* inpT, const float* ctx, const float* haP,
                                       const float* awih, const float* awhh, int j0, int l16, int g16) {
    Src s;
    if (kb < 256)      { s.irs = 256;  s.ap = inpT + g16 * 4 * 256  + kb + l16 * 4;          s.wrs = 768;  s.wp = awih + (size_t)j0 * 768  + kb + l16 * 4; }
    else if (kb < 768) { s.irs = 512;  s.ap = ctx  + g16 * 4 * 512  + (kb - 256) + l16 * 4;  s.wrs = 768;  s.wp = awih + (size_t)j0 * 768  + kb + l16 * 4; }
    else               { s.irs = 1024; s.ap = haP  + g16 * 4 * 1024 + (kb - 768) + l16 * 4;  s.wrs = 1024; s.wp = awhh + (size_t)j0 * 1024 + (kb - 768) + l16 * 4; }
    return s;
}

__device__ __forceinline__ Src dec_src(int kb, const float* haP, const float* ctx, const float* hdP2,
                                       const float* dwih, const float* dwhh, int j0, int l16, int g16) {
    Src s;
    if (kb < 1024)      { s.irs = 1024; s.ap = haP  + g16 * 4 * 1024 + kb + l16 * 4;           s.wrs = 1536; s.wp = dwih + (size_t)j0 * 1536 + kb + l16 * 4; }
    else if (kb < 1536) { s.irs = 512;  s.ap = ctx  + g16 * 4 * 512  + (kb - 1024) + l16 * 4;  s.wrs = 1536; s.wp = dwih + (size_t)j0 * 1536 + kb + l16 * 4; }
    else                { s.irs = 1024; s.ap = hdP2 + g16 * 4 * 1024 + (kb - 1536) + l16 * 4;  s.wrs = 1024; s.wp = dwhh + (size_t)j0 * 1024 + (kb - 1536) + l16 * 4; }
    return s;
}

// ---------------- precompute: pm_t[b][f][tt] ----------------
__global__ __launch_bounds__(256) void k_pm(const float* __restrict__ mem,
                                            const float* __restrict__ Wm,
                                            float* __restrict__ pm)
{
    const int bid = blockIdx.x;
    const int b = bid >> 5, ch = bid & 31;
    const int tid = threadIdx.x;
    const int tt0 = ch * 16;
    __shared__ float ml[16][512];
    for (int i = tid; i < 16 * 128; i += 256) {
        const int r = i >> 7, c4 = (i & 127) * 4;
        *(float4*)&ml[r][c4] = *(const float4*)(mem + (size_t)(b * 512 + tt0 + r) * 512 + c4);
    }
    __syncthreads();
    const int f = tid & 127, th = tid >> 7;
    float acc[8] = {0, 0, 0, 0, 0, 0, 0, 0};
    const float* wr = Wm + f * 512;
    for (int d = 0; d < 512; d += 4) {
        const float4 w4 = *(const float4*)(wr + d);
        #pragma unroll
        for (int i = 0; i < 8; ++i) {
            const float4 m4 = *(const float4*)&ml[th * 8 + i][d];
            acc[i] += w4.x * m4.x + w4.y * m4.y + w4.z * m4.z + w4.w * m4.w;
        }
    }
    #pragma unroll
    for (int i = 0; i < 8; ++i)
        pm[(size_t)(b * 128 + f) * 512 + tt0 + th * 8 + i] = acc[i];
}

// ---------------- precompute: prenet ----------------
__global__ __launch_bounds__(256) void k_prenet(const float* __restrict__ di,
                                                const float* __restrict__ W1,
                                                const float* __restrict__ W2,
                                                float* __restrict__ inp)
{
    const int t = blockIdx.x;
    const int tid = threadIdx.x;
    float* inpT = inp + (size_t)t * (NB * PRE);
    if (t == 0) {
        for (int i = tid; i < NB * PRE; i += 256) inpT[i] = 0.0f;
        return;
    }
    const int s = t - 1;
    __shared__ float xs[16][240];
    __shared__ float h1[16][256];
    for (int i = tid; i < 16 * 240; i += 256) {
        const int b = i / 240, j2 = i % 240;
        xs[b][j2] = di[(size_t)b * 48000 + (j2 % 80) * 600 + s * 3 + j2 / 80];
    }
    __syncthreads();
    const int j = tid;
    {
        float acc[16];
        #pragma unroll
        for (int b = 0; b < 16; ++b) acc[b] = 0.0f;
        const float* wr = W1 + j * 240;
        for (int k = 0; k < 240; k += 4) {
            const float4 w4 = *(const float4*)(wr + k);
            #pragma unroll
            for (int b = 0; b < 16; ++b) {
                const float4 x4 = *(const float4*)&xs[b][k];
                acc[b] += w4.x * x4.x + w4.y * x4.y + w4.z * x4.z + w4.w * x4.w;
            }
        }
        #pragma unroll
        for (int b = 0; b < 16; ++b) h1[b][j] = fmaxf(acc[b], 0.0f);
    }
    __syncthreads();
    {
        float acc[16];
        #pragma unroll
        for (int b = 0; b < 16; ++b) acc[b] = 0.0f;
        const float* wr = W2 + j * 256;
        for (int k = 0; k < 256; k += 4) {
            const float4 w4 = *(const float4*)(wr + k);
            #pragma unroll
            for (int b = 0; b < 16; ++b) {
                const float4 x4 = *(const float4*)&h1[b][k];
                acc[b] += w4.x * x4.x + w4.y * x4.y + w4.z * x4.z + w4.w * x4.w;
            }
        }
        #pragma unroll
        for (int b = 0; b < 16; ++b) inpT[b * 256 + j] = fmaxf(acc[b], 0.0f);
    }
}

// ---------------- persistent decoder kernel ----------------
__global__ __launch_bounds__(512, 2) void k_main(
    const float* __restrict__ mem,  const int* __restrict__ mlen,
    const float* __restrict__ awih, const float* __restrict__ awhh,
    const float* __restrict__ abih, const float* __restrict__ abhh,
    const float* __restrict__ dwih, const float* __restrict__ dwhh,
    const float* __restrict__ dbih, const float* __restrict__ dbhh,
    const float* __restrict__ wq,   const float* __restrict__ vat,
    const float* __restrict__ cw,   const float* __restrict__ ldw,
    const float* __restrict__ pjw,  const float* __restrict__ pjb,
    float* __restrict__ ws, float* __restrict__ out)
{
    const int tid  = threadIdx.x;
    const int bid  = blockIdx.x;
    const int wid  = tid >> 6;
    const int lane = tid & 63;
    const int l16  = lane & 15;
    const int g16  = lane >> 4;

    float* pmT  = ws + PM_OFF;
    float* inp  = ws + INP_OFF;
    float* haB  = ws + HA_OFF;
    float* hdB  = ws + HD_OFF;
    float* caB  = ws + CA_OFF;
    float* cdB  = ws + CD_OFF;
    float* ctxB = ws + CTX_OFF;
    float* wBf  = ws + WB_OFF;
    float* wcB  = ws + WC_OFF;
    float* locB = ws + LOC_OFF;
    float* peB  = ws + PE_OFF;
    unsigned* bar = (unsigned*)(ws + BAR_OFF);
    float* outMel = out;
    float* outAl  = out + 768000;

    __shared__ float smem[3072];
    unsigned gen = 0;

    for (int t = 0; t <= TDEC; ++t) {
        const int cur = t & 1, prv = cur ^ 1;
        const float* haP  = haB + prv * (NB * RNN);  // h_a(t-1)
        float*       haC  = haB + cur * (NB * RNN);  // h_a(t)
        const float* hdP2 = hdB + cur * (NB * RNN);  // h_d(t-2)
        float*       hdW  = hdB + prv * (NB * RNN);  // h_d(t-1)

        // ================= P1: attLSTM(t), decLSTM(t-1), conv(t) =================
        {
            const int j0 = bid * 4;
            const bool isDec = wid >= 4;
            const int q = wid & 3;
            const bool act = isDec ? (t >= 1) : (t < TDEC);
            if (act) {
                float acc[16][4];
                #pragma unroll
                for (int r = 0; r < 16; ++r) { acc[r][0] = 0; acc[r][1] = 0; acc[r][2] = 0; acc[r][3] = 0; }
                const float* inpT = inp + (size_t)t * (NB * PRE);
                if (!isDec) {
                    Src s = att_src(q * 448, inpT, ctxB, haP, awih, awhh, j0, l16, g16);
                    A16 buf = load_slice(s.ap, s.irs);
                    #pragma unroll
                    for (int it = 0; it < 7; ++it) {
                        Src sn; A16 nxt;
                        if (it < 6) {
                            sn = att_src(q * 448 + (it + 1) * 64, inpT, ctxB, haP, awih, awhh, j0, l16, g16);
                            nxt = load_slice(sn.ap, sn.irs);
                        }
                        fma_slice(acc, s.wp, s.wrs, buf);
                        if (it < 6) { s = sn; buf = nxt; }
                    }
                } else {
                    Src s = dec_src(q * 640, haP, ctxB, hdP2, dwih, dwhh, j0, l16, g16);
                    A16 buf = load_slice(s.ap, s.irs);
                    #pragma unroll
                    for (int it = 0; it < 10; ++it) {
                        Src sn; A16 nxt;
                        if (it < 9) {
                            sn = dec_src(q * 640 + (it + 1) * 64, haP, ctxB, hdP2, dwih, dwhh, j0, l16, g16);
                            nxt = load_slice(sn.ap, sn.irs);
                        }
                        fma_slice(acc, s.wp, s.wrs, buf);
                        if (it < 9) { s = sn; buf = nxt; }
                    }
                }
                #pragma unroll
                for (int m = 1; m <= 8; m <<= 1) {
                    #pragma unroll
                    for (int r = 0; r < 16; ++r) {
                        #pragma unroll
                        for (int b2 = 0; b2 < 4; ++b2)
                            acc[r][b2] += __shfl_xor(acc[r][b2], m, 16);
                    }
                }
                if (l16 == 0) {
                    #pragma unroll
                    for (int r = 0; r < 16; ++r) {
                        #pragma unroll
                        for (int b2 = 0; b2 < 4; ++b2)
                            smem[(wid * 16 + r) * 16 + g16 * 4 + b2] = acc[r][b2];
                    }
                }
            }
            __syncthreads();
            if (tid < 128) {
                const int isd = tid >> 6;
                const int cell = tid & 63;
                const int jl = cell >> 4, b = cell & 15;
                const bool act2 = isd ? (t >= 1) : (t < TDEC);
                if (act2) {
                    const int j = j0 + jl;
                    const float* bih = isd ? dbih : abih;
                    const float* bhh = isd ? dbhh : abhh;
                    float g4[4];
                    #pragma unroll
                    for (int g = 0; g < 4; ++g) {
                        const int r = jl * 4 + g;
                        float s = 0;
                        #pragma unroll
                        for (int w = 0; w < 4; ++w) s += smem[((isd * 4 + w) * 16 + r) * 16 + b];
                        g4[g] = s + bih[g * 1024 + j] + bhh[g * 1024 + j];
                    }
                    float* cb = isd ? cdB : caB;
                    float* hb = isd ? hdW : haC;
                    const float ii = sigm(g4[0]);
                    const float ff = sigm(g4[1]);
                    const float gg = tanh_f(g4[2]);
                    const float oo = sigm(g4[3]);
                    const float co = cb[b * RNN + j];
                    const float cn = ff * co + ii * gg;
                    cb[b * RNN + j] = cn;
                    stc4(&hb[b * RNN + j], oo * tanh_f(cn));
                }
            }
            // stage w / w_cum for conv into LDS (coherent reads)
            if (t < TDEC) {
                const int b = bid >> 4;
                float* wsh = smem + 2048;
                if (tid < 256) {
                    F2u v; v.u = ldc8(wBf + b * 512 + tid * 2);
                    wsh[tid * 2] = v.f[0]; wsh[tid * 2 + 1] = v.f[1];
                } else {
                    F2u v; v.u = ldc8(wcB + b * 512 + (tid - 256) * 2);
                    wsh[512 + (tid - 256) * 2] = v.f[0]; wsh[512 + (tid - 256) * 2 + 1] = v.f[1];
                }
            }
            __syncthreads();
            if (t < TDEC) {
                const int b = bid >> 4;
                const int c = (bid & 15) * 2 + (tid >> 8);
                const int ttb = tid & 255;
                const float* cwc = cw + c * 62;
                const float* wsh = smem + 2048;
                #pragma unroll
                for (int h = 0; h < 2; ++h) {
                    const int tt = ttb + h * 256;
                    float a = 0;
                    #pragma unroll
                    for (int kk = 0; kk < 31; ++kk) {
                        const int ix = tt + kk - 15;
                        if (ix >= 0 && ix < 512)
                            a += wsh[ix] * cwc[kk] + wsh[512 + ix] * cwc[31 + kk];
                    }
                    stc4(&locB[(size_t)(b * 512 + tt) * 32 + c], a);
                }
            }
        }
        grid_barrier(bar, gen); ++gen;

        // ================= P2: q-slice + partial energies; proj(t-1) =================
        {
            if (t < TDEC) {
                const int b = bid >> 4, fc = bid & 15;
                {
                    const int f = fc * 8 + wid;
                    const float* wqr = wq + f * 1024;
                    const float* hac = haC + b * 1024;
                    float aq = 0;
                    #pragma unroll
                    for (int it = 0; it < 4; ++it) {
                        const int k = it * 256 + lane * 4;
                        const float4 w4 = *(const float4*)(wqr + k);
                        F2u h0, h1; h0.u = ldc8(hac + k); h1.u = ldc8(hac + k + 2);
                        aq += w4.x * h0.f[0] + w4.y * h0.f[1] + w4.z * h1.f[0] + w4.w * h1.f[1];
                    }
                    #pragma unroll
                    for (int m = 1; m <= 32; m <<= 1) aq += __shfl_xor(aq, m, 64);
                    if (lane == 0) smem[wid] = aq;
                }
                __syncthreads();
                {
                    const int tt = tid;
                    float lc[32];
                    const float* lr = locB + (size_t)(b * 512 + tt) * 32;
                    #pragma unroll
                    for (int i = 0; i < 16; ++i) {
                        F2u v; v.u = ldc8(lr + i * 2);
                        lc[i * 2] = v.f[0]; lc[i * 2 + 1] = v.f[1];
                    }
                    const float* pmr = pmT + (size_t)(b * 128 + fc * 8) * 512;
                    float pes = 0;
                    #pragma unroll
                    for (int f_ = 0; f_ < 8; ++f_) {
                        const float* lw = ldw + (fc * 8 + f_) * 32;
                        float pl = 0;
                        #pragma unroll
                        for (int c2 = 0; c2 < 32; ++c2) pl += lc[c2] * lw[c2];
                        const float x = smem[f_] + pl + pmr[f_ * 512 + tt];
                        pes += vat[fc * 8 + f_] * tanh_f(x);
                    }
                    stc4(&peB[(size_t)(b * 512 + tt) * 16 + fc], pes);
                }
            }
            if (t >= 1 && bid < 240) {
                const int jo = bid;
                const int b0 = wid * 2, b1 = b0 + 1;
                const float* pwr = pjw + (size_t)jo * 1536;
                float a0 = 0, a1 = 0;
                #pragma unroll
                for (int it = 0; it < 6; ++it) {
                    const int k = it * 256 + lane * 4;
                    const float4 w4 = *(const float4*)(pwr + k);
                    const float* s0 = (it < 4) ? (hdW + b0 * 1024 + k) : (ctxB + b0 * 512 + (k - 1024));
                    const float* s1 = (it < 4) ? (hdW + b1 * 1024 + k) : (ctxB + b1 * 512 + (k - 1024));
                    F2u x0a, x0b, x1a, x1b;
                    x0a.u = ldc8(s0); x0b.u = ldc8(s0 + 2);
                    x1a.u = ldc8(s1); x1b.u = ldc8(s1 + 2);
                    a0 += w4.x * x0a.f[0] + w4.y * x0a.f[1] + w4.z * x0b.f[0] + w4.w * x0b.f[1];
                    a1 += w4.x * x1a.f[0] + w4.y * x1a.f[1] + w4.z * x1b.f[0] + w4.w * x1b.f[1];
                }
                #pragma unroll
                for (int m = 1; m <= 32; m <<= 1) { a0 += __shfl_xor(a0, m, 64); a1 += __shfl_xor(a1, m, 64); }
                if (lane == 0) {
                    const int m_ = jo % 80;
                    const int u = (t - 1) * 3 + jo / 80;
                    const float bv = pjb[jo];
                    outMel[(size_t)b0 * 48000 + m_ * 600 + u] = a0 + bv;
                    outMel[(size_t)b1 * 48000 + m_ * 600 + u] = a1 + bv;
                }
            }
        }
        if (t == TDEC) break;
        grid_barrier(bar, gen); ++gen;

        // ================= P3: softmax + context + w updates (one block per b) =================
        {
            if (bid < NB) {
                const int b = bid;
                float* pl_ = smem;        // [512]
                float* red = smem + 512;  // [9]
                const int tt = tid;
                float e = 0;
                const float* per = peB + (size_t)(b * 512 + tt) * 16;
                #pragma unroll
                for (int i = 0; i < 8; ++i) { F2u v; v.u = ldc8(per + i * 2); e += v.f[0] + v.f[1]; }
                const float p = (tt < mlen[b]) ? __expf(e) : 0.0f;
                pl_[tt] = p;
                float s = p;
                #pragma unroll
                for (int m = 1; m <= 32; m <<= 1) s += __shfl_xor(s, m, 64);
                if (lane == 0) red[wid] = s;
                __syncthreads();
                if (tid == 0) {
                    float d = 0;
                    #pragma unroll
                    for (int w = 0; w < 8; ++w) d += red[w];
                    red[8] = 1.0f / d;
                }
                __syncthreads();
                const float rd = red[8];
                {
                    const int d = tid;
                    const float* mr = mem + (size_t)b * (512 * 512);
                    float a = 0;
                    for (int t2 = 0; t2 < 512; t2 += 4) {
                        const float4 p4 = *(const float4*)&pl_[t2];
                        a += p4.x * mr[(size_t)(t2 + 0) * 512 + d];
                        a += p4.y * mr[(size_t)(t2 + 1) * 512 + d];
                        a += p4.z * mr[(size_t)(t2 + 2) * 512 + d];
                        a += p4.w * mr[(size_t)(t2 + 3) * 512 + d];
                    }
                    stc4(&ctxB[b * 512 + d], a * rd);
                }
                {
                    const float wn = pl_[tt] * rd;
                    stc4(&wBf[b * 512 + tt], wn);
                    stc4(&wcB[b * 512 + tt], ldc4(&wcB[b * 512 + tt]) + wn);
                    outAl[(size_t)b * (200 * 512) + (size_t)t * 512 + tt] = wn;
                }
            }
            grid_barrier(bar, gen); ++gen;
        }
    }
}

extern "C" void kernel_launch(void* const* d_in, const int* in_sizes, int n_in,
                              void* d_out, int out_size, void* d_ws, size_t ws_size,
                              hipStream_t stream)
{
    (void)in_sizes; (void)n_in; (void)out_size; (void)ws_size;
    const float* mem  = (const float*)d_in[0];
    const float* di   = (const float*)d_in[1];
    const int*   mlen = (const int*)d_in[2];
    const float* pw1  = (const float*)d_in[3];
    const float* pw2  = (const float*)d_in[4];
    const float* awih = (const float*)d_in[5];
    const float* awhh = (const float*)d_in[6];
    const float* abih = (const float*)d_in[7];
    const float* abhh = (const float*)d_in[8];
    const float* dwih = (const float*)d_in[9];
    const float* dwhh = (const float*)d_in[10];
    const float* dbih = (const float*)d_in[11];
    const float* dbhh = (const float*)d_in[12];
    const float* wqp  = (const float*)d_in[13];
    const float* wmp  = (const float*)d_in[14];
    const float* vat  = (const float*)d_in[15];
    const float* cwp  = (const float*)d_in[16];
    const float* ldwp = (const float*)d_in[17];
    const float* pjw  = (const float*)d_in[18];
    const float* pjb  = (const float*)d_in[19];
    float* ws  = (float*)d_ws;
    float* out = (float*)d_out;

    hipMemsetAsync(ws + HA_OFF, 0, ZLEN_F * sizeof(float), stream);
    hipLaunchKernelGGL(k_pm, dim3(512), dim3(256), 0, stream, mem, wmp, ws + PM_OFF);
    hipLaunchKernelGGL(k_prenet, dim3(200), dim3(256), 0, stream, di, pw1, pw2, ws + INP_OFF);

    void* args[] = { (void*)&mem, (void*)&mlen, (void*)&awih, (void*)&awhh,
                     (void*)&abih, (void*)&abhh, (void*)&dwih, (void*)&dwhh,
                     (void*)&dbih, (void*)&dbhh, (void*)&wqp, (void*)&vat,
                     (void*)&cwp, (void*)&ldwp, (void*)&pjw, (void*)&pjb,
                     (void*)&ws, (void*)&out };
    hipLaunchCooperativeKernel((const void*)k_main, dim3(256), dim3(512), args, 0, stream);
}

// Round 5
// 48274.084 us; speedup vs baseline: 2.2202x; 1.7394x over previous
//
#include <hip/hip_runtime.h>

// ---------------- problem constants ----------------
#define TDEC   200
#define NB     16
#define PRE    256
#define RNN    1024

// ---------------- ws layout (float offsets) ----------------
#define PM_OFF   0u          // pm[16][128][512]
#define INP_OFF  1048576u    // inp[200][16][256]
#define HA_OFF   1867776u    // h_a[2][16][1024]
#define HD_OFF   1900544u    // h_d[2][16][1024]
#define CTX_OFF  1933312u    // ctx[2][16][512]
#define WB_OFF   1949696u    // w[16][512]
#define WC_OFF   1957888u    // wcum[16][512]
#define BAR_OFF  1966080u    // barrier (576 u32 + pad)
#define LOC_OFF  1966848u    // loc[16][512][32]
#define PE_OFF   2228992u    // pe[16][16][512]
#define ZLEN_F   99072u      // zero HA..LOC start

typedef unsigned long long u64;

__device__ __forceinline__ float sigm(float x)   { return 1.0f / (1.0f + __expf(-x)); }
__device__ __forceinline__ float tanh_f(float x) { return 1.0f - 2.0f / (__expf(2.0f * x) + 1.0f); }

// scalar coherent (agent-scope, compiler-managed waitcnt)
__device__ __forceinline__ float ldc4(const float* p) {
    return __hip_atomic_load((float*)p, __ATOMIC_RELAXED, __HIP_MEMORY_SCOPE_AGENT);
}
__device__ __forceinline__ void stc4(float* p, float v) {
    __hip_atomic_store(p, v, __ATOMIC_RELAXED, __HIP_MEMORY_SCOPE_AGENT);
}
// 16B coherent store as 2x dwordx2 (128-bit asm inputs unsupported)
__device__ __forceinline__ void stg16(float* p, float4 v) {
    union { float f[2]; u64 u; } lo, hi;
    lo.f[0] = v.x; lo.f[1] = v.y; hi.f[0] = v.z; hi.f[1] = v.w;
    __hip_atomic_store((u64*)p,     lo.u, __ATOMIC_RELAXED, __HIP_MEMORY_SCOPE_AGENT);
    __hip_atomic_store((u64*)p + 1, hi.u, __ATOMIC_RELAXED, __HIP_MEMORY_SCOPE_AGENT);
}

// 4 coherent 16B loads from 4 pointers + drain (self-contained, no tied operands)
#define LOAD4P_WAIT0(d0,d1,d2,d3,p0,p1,p2,p3) \
  asm volatile("global_load_dwordx4 %0, %4, off sc0 sc1\n\t" \
               "global_load_dwordx4 %1, %5, off sc0 sc1\n\t" \
               "global_load_dwordx4 %2, %6, off sc0 sc1\n\t" \
               "global_load_dwordx4 %3, %7, off sc0 sc1\n\t" \
               "s_waitcnt vmcnt(0)" \
    : "=&v"(d0),"=&v"(d1),"=&v"(d2),"=&v"(d3) \
    : "v"(p0),"v"(p1),"v"(p2),"v"(p3) : "memory")

// 4 loads at base+byte offsets {0,1024,2048,3072} + wait (self-contained)
#define LOAD4X1024_WAIT0(d0,d1,d2,d3,p) \
  asm volatile("global_load_dwordx4 %0, %4, off sc0 sc1\n\t" \
               "global_load_dwordx4 %1, %4, off offset:1024 sc0 sc1\n\t" \
               "global_load_dwordx4 %2, %4, off offset:2048 sc0 sc1\n\t" \
               "global_load_dwordx4 %3, %4, off offset:3072 sc0 sc1\n\t" \
               "s_waitcnt vmcnt(0)" \
    : "=&v"(d0),"=&v"(d1),"=&v"(d2),"=&v"(d3) : "v"(p) : "memory")

// 8 loads covering 128B from base + wait (self-contained)
#define LOAD8X16_WAIT0(d0,d1,d2,d3,d4,d5,d6,d7,p) \
  asm volatile("global_load_dwordx4 %0, %8, off sc0 sc1\n\t" \
               "global_load_dwordx4 %1, %8, off offset:16 sc0 sc1\n\t" \
               "global_load_dwordx4 %2, %8, off offset:32 sc0 sc1\n\t" \
               "global_load_dwordx4 %3, %8, off offset:48 sc0 sc1\n\t" \
               "global_load_dwordx4 %4, %8, off offset:64 sc0 sc1\n\t" \
               "global_load_dwordx4 %5, %8, off offset:80 sc0 sc1\n\t" \
               "global_load_dwordx4 %6, %8, off offset:96 sc0 sc1\n\t" \
               "global_load_dwordx4 %7, %8, off offset:112 sc0 sc1\n\t" \
               "s_waitcnt vmcnt(0)" \
    : "=&v"(d0),"=&v"(d1),"=&v"(d2),"=&v"(d3),"=&v"(d4),"=&v"(d5),"=&v"(d6),"=&v"(d7) \
    : "v"(p) : "memory")

// ---- relaxed monotonic 2-level grid barrier (256 blocks) ----
// Entry drain: compiler can't see asm VMEM ops, so force vmcnt(0) ourselves
// before the flag RMW (release). Acquire side: data re-read via sc loads (LLC).
__device__ __forceinline__ void grid_barrier(unsigned* bar, unsigned g)
{
    asm volatile("s_waitcnt vmcnt(0)" ::: "memory");
    __syncthreads();
    if (threadIdx.x == 0) {
        const int leaf = (blockIdx.x & 15) * 32;
        const unsigned tgt = g * 16u + 15u;
        if (__hip_atomic_fetch_add(&bar[leaf], 1u, __ATOMIC_RELAXED, __HIP_MEMORY_SCOPE_AGENT) == tgt) {
            if (__hip_atomic_fetch_add(&bar[512], 1u, __ATOMIC_RELAXED, __HIP_MEMORY_SCOPE_AGENT) == tgt) {
                __hip_atomic_store(&bar[544], g + 1u, __ATOMIC_RELAXED, __HIP_MEMORY_SCOPE_AGENT);
            } else {
                while (__hip_atomic_load(&bar[544], __ATOMIC_RELAXED, __HIP_MEMORY_SCOPE_AGENT) != g + 1u)
                    __builtin_amdgcn_s_sleep(4);
            }
        } else {
            while (__hip_atomic_load(&bar[544], __ATOMIC_RELAXED, __HIP_MEMORY_SCOPE_AGENT) != g + 1u)
                __builtin_amdgcn_s_sleep(4);
        }
    }
    __syncthreads();
}

struct WSrc { const float* wp; const float* a0; const float* a1; const float* a2; const float* a3; int wrs; };

__device__ __forceinline__ WSrc resolve_att(int win, int j0, int l16, int g16,
    const float* awih, const float* awhh, const float* inpT, const float* ctxP, const float* haP)
{
    WSrc s; const int col = win * 64; const float* ab; int ars;
    if (col < 256)      { s.wrs = 768;  s.wp = awih + (size_t)j0 * 768  + col + l16 * 4;         ab = inpT + col;         ars = 256; }
    else if (col < 768) { s.wrs = 768;  s.wp = awih + (size_t)j0 * 768  + col + l16 * 4;         ab = ctxP + (col - 256); ars = 512; }
    else                { s.wrs = 1024; s.wp = awhh + (size_t)j0 * 1024 + (col - 768) + l16 * 4; ab = haP + (col - 768);  ars = 1024; }
    const float* base = ab + l16 * 4 + g16 * 4 * ars;
    s.a0 = base; s.a1 = base + ars; s.a2 = base + 2 * ars; s.a3 = base + 3 * ars;
    return s;
}

__device__ __forceinline__ WSrc resolve_dec(int win, int j0, int l16, int g16,
    const float* dwih, const float* dwhh, const float* haP, const float* ctxP, const float* hdP2)
{
    WSrc s; const int col = win * 64; const float* ab; int ars;
    if (col < 1024)      { s.wrs = 1536; s.wp = dwih + (size_t)j0 * 1536 + col + l16 * 4;          ab = haP + col;           ars = 1024; }
    else if (col < 1536) { s.wrs = 1536; s.wp = dwih + (size_t)j0 * 1536 + col + l16 * 4;          ab = ctxP + (col - 1024); ars = 512; }
    else                 { s.wrs = 1024; s.wp = dwhh + (size_t)j0 * 1024 + (col - 1536) + l16 * 4; ab = hdP2 + (col - 1536); ars = 1024; }
    const float* base = ab + l16 * 4 + g16 * 4 * ars;
    s.a0 = base; s.a1 = base + ars; s.a2 = base + 2 * ars; s.a3 = base + 3 * ars;
    return s;
}

__device__ __forceinline__ void fma16(float acc[16][4], const float* wp, int wrs, const float4 av[4])
{
    #pragma unroll
    for (int r = 0; r < 16; ++r) {
        const float4 w4 = *(const float4*)(wp + (size_t)((r & 3) * 1024 + (r >> 2)) * wrs);
        #pragma unroll
        for (int b = 0; b < 4; ++b)
            acc[r][b] += w4.x * av[b].x + w4.y * av[b].y + w4.z * av[b].z + w4.w * av[b].w;
    }
}

// ---------------- precompute: pm[b][f][tt] ----------------
__global__ __launch_bounds__(256) void k_pm(const float* __restrict__ mem,
                                            const float* __restrict__ Wm,
                                            float* __restrict__ pm)
{
    const int bid = blockIdx.x;
    const int b = bid >> 5, ch = bid & 31;
    const int tid = threadIdx.x;
    const int tt0 = ch * 16;
    __shared__ float ml[16][512];
    for (int i = tid; i < 16 * 128; i += 256) {
        const int r = i >> 7, c4 = (i & 127) * 4;
        *(float4*)&ml[r][c4] = *(const float4*)(mem + (size_t)(b * 512 + tt0 + r) * 512 + c4);
    }
    __syncthreads();
    const int f = tid & 127, th = tid >> 7;
    float acc[8] = {0, 0, 0, 0, 0, 0, 0, 0};
    const float* wr = Wm + f * 512;
    for (int d = 0; d < 512; d += 4) {
        const float4 w4 = *(const float4*)(wr + d);
        #pragma unroll
        for (int i = 0; i < 8; ++i) {
            const float4 m4 = *(const float4*)&ml[th * 8 + i][d];
            acc[i] += w4.x * m4.x + w4.y * m4.y + w4.z * m4.z + w4.w * m4.w;
        }
    }
    #pragma unroll
    for (int i = 0; i < 8; ++i)
        pm[(size_t)(b * 128 + f) * 512 + tt0 + th * 8 + i] = acc[i];
}

// ---------------- precompute: prenet ----------------
__global__ __launch_bounds__(256) void k_prenet(const float* __restrict__ di,
                                                const float* __restrict__ W1,
                                                const float* __restrict__ W2,
                                                float* __restrict__ inp)
{
    const int t = blockIdx.x;
    const int tid = threadIdx.x;
    float* inpT = inp + (size_t)t * (NB * PRE);
    if (t == 0) {
        for (int i = tid; i < NB * PRE; i += 256) inpT[i] = 0.0f;
        return;
    }
    const int s = t - 1;
    __shared__ float xs[16][240];
    __shared__ float h1[16][256];
    for (int i = tid; i < 16 * 240; i += 256) {
        const int b = i / 240, j2 = i % 240;
        xs[b][j2] = di[(size_t)b * 48000 + (j2 % 80) * 600 + s * 3 + j2 / 80];
    }
    __syncthreads();
    const int j = tid;
    {
        float acc[16];
        #pragma unroll
        for (int b = 0; b < 16; ++b) acc[b] = 0.0f;
        const float* wr = W1 + j * 240;
        for (int k = 0; k < 240; k += 4) {
            const float4 w4 = *(const float4*)(wr + k);
            #pragma unroll
            for (int b = 0; b < 16; ++b) {
                const float4 x4 = *(const float4*)&xs[b][k];
                acc[b] += w4.x * x4.x + w4.y * x4.y + w4.z * x4.z + w4.w * x4.w;
            }
        }
        #pragma unroll
        for (int b = 0; b < 16; ++b) h1[b][j] = fmaxf(acc[b], 0.0f);
    }
    __syncthreads();
    {
        float acc[16];
        #pragma unroll
        for (int b = 0; b < 16; ++b) acc[b] = 0.0f;
        const float* wr = W2 + j * 256;
        for (int k = 0; k < 256; k += 4) {
            const float4 w4 = *(const float4*)(wr + k);
            #pragma unroll
            for (int b = 0; b < 16; ++b) {
                const float4 x4 = *(const float4*)&h1[b][k];
                acc[b] += w4.x * x4.x + w4.y * x4.y + w4.z * x4.z + w4.w * x4.w;
            }
        }
        #pragma unroll
        for (int b = 0; b < 16; ++b) inpT[b * 256 + j] = fmaxf(acc[b], 0.0f);
    }
}

// ---------------- persistent decoder kernel: 256 blocks x 512 threads ----------------
__global__ __launch_bounds__(512, 2) void k_main(
    const float* __restrict__ mem,  const int* __restrict__ mlen,
    const float* __restrict__ awih, const float* __restrict__ awhh,
    const float* __restrict__ abih, const float* __restrict__ abhh,
    const float* __restrict__ dwih, const float* __restrict__ dwhh,
    const float* __restrict__ dbih, const float* __restrict__ dbhh,
    const float* __restrict__ wq,   const float* __restrict__ vat,
    const float* __restrict__ cw,   const float* __restrict__ ldw,
    const float* __restrict__ pjw,  const float* __restrict__ pjb,
    float* __restrict__ ws, float* __restrict__ out)
{
    const int tid  = threadIdx.x;
    const int bid  = blockIdx.x;
    const int wid  = tid >> 6;
    const int lane = tid & 63;
    const int l16  = lane & 15;
    const int g16  = lane >> 4;

    float* pmT  = ws + PM_OFF;
    float* inp  = ws + INP_OFF;
    float* haB  = ws + HA_OFF;
    float* hdB  = ws + HD_OFF;
    float* ctxB = ws + CTX_OFF;
    float* wBf  = ws + WB_OFF;
    float* wcB  = ws + WC_OFF;
    float* locB = ws + LOC_OFF;
    float* peB  = ws + PE_OFF;
    unsigned* bar = (unsigned*)(ws + BAR_OFF);
    float* outMel = out;
    float* outAl  = out + 768000;

    __shared__ float smem[4288];
    unsigned gen = 0;
    float c_reg = 0.0f;   // persistent LSTM cell state (att or dec), owned by tid<128

    const bool isAtt = (bid < 128);
    const int j0 = (isAtt ? bid : bid - 128) * 8;

    for (int t = 0; t <= TDEC; ++t) {
        const float* haP  = haB + ((t + 1) & 1) * (NB * RNN);   // h_a(t-1)
        float*       haC  = haB + (t & 1) * (NB * RNN);         // h_a(t)
        const float* hdP2 = hdB + (t & 1) * (NB * RNN);         // h_d(t-2)
        float*       hdW  = hdB + ((t + 1) & 1) * (NB * RNN);   // h_d(t-1)
        const float* ctxP = ctxB + ((t + 1) & 1) * (NB * 512);  // ctx(t-1)
        float*       ctxC = ctxB + (t & 1) * (NB * 512);        // ctx(t)
        const float* inpT = inp + (size_t)t * (NB * PRE);

        // ================= P1 =================
        if (isAtt) {
            const bool act = (t < TDEC);
            const int cb = bid >> 3, tt0 = (bid & 7) * 64;  // conv block coords
            if (act && tid < 96) {  // stage w/wcum (+halo, zero-pad) for conv
                const int ix = tt0 - 16 + tid;
                const bool v = (ix >= 0 && ix < 512);
                smem[4096 + tid] = v ? ldc4(wBf + cb * 512 + ix) : 0.0f;
                smem[4192 + tid] = v ? ldc4(wcB + cb * 512 + ix) : 0.0f;
            }
            if (act) {
                float accA[16][4], accB[16][4];
                #pragma unroll
                for (int r = 0; r < 16; ++r)
                    #pragma unroll
                    for (int b = 0; b < 4; ++b) { accA[r][b] = 0.0f; accB[r][b] = 0.0f; }
                const int nw = (wid < 4) ? 4 : 3;
                for (int wi = 0; wi < nw; ++wi) {
                    WSrc s = resolve_att(wid + wi * 8, j0, l16, g16, awih, awhh, inpT, ctxP, haP);
                    float4 c0, c1, c2, c3;
                    LOAD4P_WAIT0(c0, c1, c2, c3, s.a0, s.a1, s.a2, s.a3);
                    const float4 av[4] = {c0, c1, c2, c3};
                    fma16(accA, s.wp, s.wrs, av);
                    fma16(accB, s.wp + 4 * (size_t)s.wrs, s.wrs, av);
                }
                #pragma unroll
                for (int rg = 0; rg < 2; ++rg) {
                    float (*ac)[4] = rg ? accB : accA;
                    #pragma unroll
                    for (int m = 1; m <= 8; m <<= 1)
                        #pragma unroll
                        for (int r = 0; r < 16; ++r)
                            #pragma unroll
                            for (int b = 0; b < 4; ++b)
                                ac[r][b] += __shfl_xor(ac[r][b], m, 16);
                    if (l16 == 0)
                        #pragma unroll
                        for (int r = 0; r < 16; ++r)
                            #pragma unroll
                            for (int b = 0; b < 4; ++b)
                                smem[((wid * 2 + rg) * 16 + r) * 16 + g16 * 4 + b] = ac[r][b];
                }
            }
            __syncthreads();
            if (act) {
                if (tid < 128) {  // att LSTM epilogue
                    const int b = tid >> 3, jl = tid & 7;
                    const int rg = jl >> 2, jq = jl & 3;
                    const int j = j0 + jl;
                    float g4[4];
                    #pragma unroll
                    for (int g = 0; g < 4; ++g) {
                        float sg = 0.0f;
                        #pragma unroll
                        for (int w = 0; w < 8; ++w)
                            sg += smem[((w * 2 + rg) * 16 + jq * 4 + g) * 16 + b];
                        g4[g] = sg + abih[g * 1024 + j] + abhh[g * 1024 + j];
                    }
                    const float ii = sigm(g4[0]), ff = sigm(g4[1]);
                    const float gg = tanh_f(g4[2]), oo = sigm(g4[3]);
                    c_reg = ff * c_reg + ii * gg;
                    stc4(&haC[b * RNN + j], oo * tanh_f(c_reg));
                }
                {   // location conv: 4 channels x 1 tt per thread
                    const int tt = tt0 + (tid >> 3);
                    const int cc0 = (tid & 7) * 4;
                    const float* wsh = smem + 4096;
                    const float* wcsh = smem + 4192;
                    float a0 = 0, a1 = 0, a2 = 0, a3 = 0;
                    #pragma unroll
                    for (int kk = 0; kk < 31; ++kk) {
                        const float wv  = wsh[(tt - tt0) + kk + 1];
                        const float wc2 = wcsh[(tt - tt0) + kk + 1];
                        a0 += wv * cw[(cc0 + 0) * 62 + kk] + wc2 * cw[(cc0 + 0) * 62 + 31 + kk];
                        a1 += wv * cw[(cc0 + 1) * 62 + kk] + wc2 * cw[(cc0 + 1) * 62 + 31 + kk];
                        a2 += wv * cw[(cc0 + 2) * 62 + kk] + wc2 * cw[(cc0 + 2) * 62 + 31 + kk];
                        a3 += wv * cw[(cc0 + 3) * 62 + kk] + wc2 * cw[(cc0 + 3) * 62 + 31 + kk];
                    }
                    stg16(&locB[(size_t)(cb * 512 + tt) * 32 + cc0], make_float4(a0, a1, a2, a3));
                }
            }
        } else {  // dec blocks
            const bool act = (t >= 1);
            if (act) {
                float accA[16][4], accB[16][4];
                #pragma unroll
                for (int r = 0; r < 16; ++r)
                    #pragma unroll
                    for (int b = 0; b < 4; ++b) { accA[r][b] = 0.0f; accB[r][b] = 0.0f; }
                #pragma unroll
                for (int wi = 0; wi < 5; ++wi) {
                    WSrc s = resolve_dec(wid + wi * 8, j0, l16, g16, dwih, dwhh, haP, ctxP, hdP2);
                    float4 c0, c1, c2, c3;
                    LOAD4P_WAIT0(c0, c1, c2, c3, s.a0, s.a1, s.a2, s.a3);
                    const float4 av[4] = {c0, c1, c2, c3};
                    fma16(accA, s.wp, s.wrs, av);
                    fma16(accB, s.wp + 4 * (size_t)s.wrs, s.wrs, av);
                }
                #pragma unroll
                for (int rg = 0; rg < 2; ++rg) {
                    float (*ac)[4] = rg ? accB : accA;
                    #pragma unroll
                    for (int m = 1; m <= 8; m <<= 1)
                        #pragma unroll
                        for (int r = 0; r < 16; ++r)
                            #pragma unroll
                            for (int b = 0; b < 4; ++b)
                                ac[r][b] += __shfl_xor(ac[r][b], m, 16);
                    if (l16 == 0)
                        #pragma unroll
                        for (int r = 0; r < 16; ++r)
                            #pragma unroll
                            for (int b = 0; b < 4; ++b)
                                smem[((wid * 2 + rg) * 16 + r) * 16 + g16 * 4 + b] = ac[r][b];
                }
            }
            __syncthreads();
            if (act && tid < 128) {  // dec LSTM epilogue
                const int b = tid >> 3, jl = tid & 7;
                const int rg = jl >> 2, jq = jl & 3;
                const int j = j0 + jl;
                float g4[4];
                #pragma unroll
                for (int g = 0; g < 4; ++g) {
                    float sg = 0.0f;
                    #pragma unroll
                    for (int w = 0; w < 8; ++w)
                        sg += smem[((w * 2 + rg) * 16 + jq * 4 + g) * 16 + b];
                    g4[g] = sg + dbih[g * 1024 + j] + dbhh[g * 1024 + j];
                }
                const float ii = sigm(g4[0]), ff = sigm(g4[1]);
                const float gg = tanh_f(g4[2]), oo = sigm(g4[3]);
                c_reg = ff * c_reg + ii * gg;
                stc4(&hdW[b * RNN + j], oo * tanh_f(c_reg));
            }
        }
        grid_barrier(bar, gen); ++gen;

        // ================= P2: energies =================
        if (t < TDEC) {
            const int b2 = bid >> 4, fc = bid & 15;
            {   // q-GEMV: wave wid computes f = fc*8+wid
                const int f = fc * 8 + wid;
                const float* hac = haC + b2 * 1024 + lane * 4;
                float4 h0, h1, h2, h3;
                LOAD4X1024_WAIT0(h0, h1, h2, h3, hac);
                const float* wqr = wq + (size_t)f * 1024 + lane * 4;
                const float4 w0 = *(const float4*)(wqr);
                const float4 w1 = *(const float4*)(wqr + 256);
                const float4 w2 = *(const float4*)(wqr + 512);
                const float4 w3 = *(const float4*)(wqr + 768);
                float aq = w0.x * h0.x + w0.y * h0.y + w0.z * h0.z + w0.w * h0.w
                         + w1.x * h1.x + w1.y * h1.y + w1.z * h1.z + w1.w * h1.w
                         + w2.x * h2.x + w2.y * h2.y + w2.z * h2.z + w2.w * h2.w
                         + w3.x * h3.x + w3.y * h3.y + w3.z * h3.z + w3.w * h3.w;
                #pragma unroll
                for (int m = 1; m <= 32; m <<= 1) aq += __shfl_xor(aq, m, 64);
                if (lane == 0) smem[wid] = aq;
            }
            __syncthreads();
            {   // energy partials: thread = tt
                const int tt = tid;
                const float* lr = locB + (size_t)(b2 * 512 + tt) * 32;
                float4 l0, l1, l2, l3, l4, l5, l6, l7;
                LOAD8X16_WAIT0(l0, l1, l2, l3, l4, l5, l6, l7, lr);
                const float lc[32] = {
                    l0.x, l0.y, l0.z, l0.w, l1.x, l1.y, l1.z, l1.w,
                    l2.x, l2.y, l2.z, l2.w, l3.x, l3.y, l3.z, l3.w,
                    l4.x, l4.y, l4.z, l4.w, l5.x, l5.y, l5.z, l5.w,
                    l6.x, l6.y, l6.z, l6.w, l7.x, l7.y, l7.z, l7.w };
                const float* pmr = pmT + (size_t)(b2 * 128 + fc * 8) * 512 + tt;
                float pes = 0.0f;
                #pragma unroll
                for (int f_ = 0; f_ < 8; ++f_) {
                    const float* lw = ldw + (fc * 8 + f_) * 32;
                    float pl = 0.0f;
                    #pragma unroll
                    for (int c2 = 0; c2 < 32; ++c2) pl += lc[c2] * lw[c2];
                    const float x = smem[f_] + pl + pmr[f_ * 512];
                    pes += vat[fc * 8 + f_] * tanh_f(x);
                }
                stc4(peB + (size_t)(b2 * 16 + fc) * 512 + tt, pes);
            }
        }
        grid_barrier(bar, gen); ++gen;

        // ================= P3: softmax/ctx (blocks 0-63) + proj (64-183) =================
        if (bid < 64) {
            if (t < TDEC) {
                const int b3 = bid >> 2, dq = bid & 3;
                float* pl_ = smem;         // [512]
                float* red = smem + 512;   // [9]
                float* psm = smem + 528;   // [512]
                const int tt = tid;
                float e = 0.0f;
                #pragma unroll
                for (int fc = 0; fc < 16; ++fc)
                    e += ldc4(peB + (size_t)(b3 * 16 + fc) * 512 + tt);
                const float p = (tt < mlen[b3]) ? __expf(e) : 0.0f;
                pl_[tt] = p;
                float sred = p;
                #pragma unroll
                for (int m = 1; m <= 32; m <<= 1) sred += __shfl_xor(sred, m, 64);
                if (lane == 0) red[wid] = sred;
                __syncthreads();
                if (tid == 0) {
                    float d = 0.0f;
                    #pragma unroll
                    for (int w = 0; w < 8; ++w) d += red[w];
                    red[8] = 1.0f / d;
                }
                __syncthreads();
                const float rd = red[8];
                {   // ctx slice dq*128..+128
                    const int dl = tid & 127, part = tid >> 7;
                    const float* mr = mem + (size_t)b3 * (512 * 512) + dq * 128 + dl;
                    float a = 0.0f;
                    const int t0 = part * 128;
                    for (int t2 = 0; t2 < 128; ++t2)
                        a += pl_[t0 + t2] * mr[(size_t)(t0 + t2) * 512];
                    psm[dl * 4 + part] = a;
                }
                __syncthreads();
                if (tid < 128) {
                    const float a = psm[tid * 4] + psm[tid * 4 + 1] + psm[tid * 4 + 2] + psm[tid * 4 + 3];
                    stc4(&ctxC[b3 * 512 + dq * 128 + tid], a * rd);
                }
                if (dq == 0) {
                    const float wn = pl_[tt] * rd;
                    stc4(&wBf[b3 * 512 + tt], wn);
                    stc4(&wcB[b3 * 512 + tt], ldc4(&wcB[b3 * 512 + tt]) + wn);
                    outAl[(size_t)b3 * (200 * 512) + (size_t)t * 512 + tt] = wn;
                }
            }
        } else if (bid < 184) {
            if (t >= 1) {
                const int jo = (bid - 64) * 2 + (wid >> 2);
                const int bq = (wid & 3) * 4;
                const float* pwr = pjw + (size_t)jo * 1536 + lane * 4;
                float a0 = 0, a1 = 0, a2 = 0, a3 = 0;
                #pragma unroll
                for (int it = 0; it < 6; ++it) {
                    const int k = it * 256 + lane * 4;
                    const float* q0; const float* q1; const float* q2; const float* q3;
                    if (it < 4) {
                        q0 = hdW + (bq + 0) * 1024 + k; q1 = hdW + (bq + 1) * 1024 + k;
                        q2 = hdW + (bq + 2) * 1024 + k; q3 = hdW + (bq + 3) * 1024 + k;
                    } else {
                        const int k2 = k - 1024;
                        q0 = ctxP + (bq + 0) * 512 + k2; q1 = ctxP + (bq + 1) * 512 + k2;
                        q2 = ctxP + (bq + 2) * 512 + k2; q3 = ctxP + (bq + 3) * 512 + k2;
                    }
                    float4 c0, c1, c2, c3;
                    LOAD4P_WAIT0(c0, c1, c2, c3, q0, q1, q2, q3);
                    const float4 w4 = *(const float4*)(pwr + it * 256);
                    a0 += w4.x * c0.x + w4.y * c0.y + w4.z * c0.z + w4.w * c0.w;
                    a1 += w4.x * c1.x + w4.y * c1.y + w4.z * c1.z + w4.w * c1.w;
                    a2 += w4.x * c2.x + w4.y * c2.y + w4.z * c2.z + w4.w * c2.w;
                    a3 += w4.x * c3.x + w4.y * c3.y + w4.z * c3.z + w4.w * c3.w;
                }
                #pragma unroll
                for (int m = 1; m <= 32; m <<= 1) {
                    a0 += __shfl_xor(a0, m, 64); a1 += __shfl_xor(a1, m, 64);
                    a2 += __shfl_xor(a2, m, 64); a3 += __shfl_xor(a3, m, 64);
                }
                if (lane == 0) {
                    const int m_ = jo % 80;
                    const int u = (t - 1) * 3 + jo / 80;
                    const float bv = pjb[jo];
                    outMel[(size_t)(bq + 0) * 48000 + m_ * 600 + u] = a0 + bv;
                    outMel[(size_t)(bq + 1) * 48000 + m_ * 600 + u] = a1 + bv;
                    outMel[(size_t)(bq + 2) * 48000 + m_ * 600 + u] = a2 + bv;
                    outMel[(size_t)(bq + 3) * 48000 + m_ * 600 + u] = a3 + bv;
                }
            }
        }
        grid_barrier(bar, gen); ++gen;
    }
}

extern "C" void kernel_launch(void* const* d_in, const int* in_sizes, int n_in,
                              void* d_out, int out_size, void* d_ws, size_t ws_size,
                              hipStream_t stream)
{
    (void)in_sizes; (void)n_in; (void)out_size; (void)ws_size;
    const float* mem  = (const float*)d_in[0];
    const float* di   = (const float*)d_in[1];
    const int*   mlen = (const int*)d_in[2];
    const float* pw1  = (const float*)d_in[3];
    const float* pw2  = (const float*)d_in[4];
    const float* awih = (const float*)d_in[5];
    const float* awhh = (const float*)d_in[6];
    const float* abih = (const float*)d_in[7];
    const float* abhh = (const float*)d_in[8];
    const float* dwih = (const float*)d_in[9];
    const float* dwhh = (const float*)d_in[10];
    const float* dbih = (const float*)d_in[11];
    const float* dbhh = (const float*)d_in[12];
    const float* wqp  = (const float*)d_in[13];
    const float* wmp  = (const float*)d_in[14];
    const float* vat  = (const float*)d_in[15];
    const float* cwp  = (const float*)d_in[16];
    const float* ldwp = (const float*)d_in[17];
    const float* pjw  = (const float*)d_in[18];
    const float* pjb  = (const float*)d_in[19];
    float* ws  = (float*)d_ws;
    float* out = (float*)d_out;

    hipMemsetAsync(ws + HA_OFF, 0, ZLEN_F * sizeof(float), stream);
    hipLaunchKernelGGL(k_pm, dim3(512), dim3(256), 0, stream, mem, wmp, ws + PM_OFF);
    hipLaunchKernelGGL(k_prenet, dim3(200), dim3(256), 0, stream, di, pw1, pw2, ws + INP_OFF);

    void* args[] = { (void*)&mem, (void*)&mlen, (void*)&awih, (void*)&awhh,
                     (void*)&abih, (void*)&abhh, (void*)&dwih, (void*)&dwhh,
                     (void*)&dbih, (void*)&dbhh, (void*)&wqp, (void*)&vat,
                     (void*)&cwp, (void*)&ldwp, (void*)&pjw, (void*)&pjb,
                     (void*)&ws, (void*)&out };
    hipLaunchCooperativeKernel((const void*)k_main, dim3(256), dim3(512), args, 0, stream);
}